// Round 1
// baseline (528.484 us; speedup 1.0000x reference)
//
#include <hip/hip_runtime.h>
#include <cstdint>
#include <cstddef>

// ---------------- CSR build ----------------

__global__ void hist_kernel(const int* __restrict__ dst, int* __restrict__ counts, int E) {
    int i = blockIdx.x * blockDim.x + threadIdx.x;
    if (i < E) atomicAdd(&counts[dst[i]], 1);
}

// 2048 elements per block (256 threads x 8), exclusive scan within block
__global__ void scan1_kernel(const int* __restrict__ counts, int* __restrict__ off,
                             int* __restrict__ bsum, int N) {
    __shared__ int sh[256];
    const int tid = threadIdx.x;
    const int base = blockIdx.x * 2048 + tid * 8;
    int v[8];
    int tsum = 0;
#pragma unroll
    for (int j = 0; j < 8; ++j) {
        int i = base + j;
        v[j] = (i < N) ? counts[i] : 0;
        tsum += v[j];
    }
    sh[tid] = tsum;
    __syncthreads();
    for (int d = 1; d < 256; d <<= 1) {
        int t = (tid >= d) ? sh[tid - d] : 0;
        __syncthreads();
        sh[tid] += t;
        __syncthreads();
    }
    int excl = sh[tid] - tsum;
    if (tid == 255) bsum[blockIdx.x] = sh[255];
    int run = excl;
#pragma unroll
    for (int j = 0; j < 8; ++j) {
        int i = base + j;
        if (i < N) off[i] = run;
        run += v[j];
    }
}

// single-wave scan of block sums (NB <= 64)
__global__ void scan2_kernel(const int* __restrict__ bsum, int* __restrict__ boff, int NB) {
    int lane = threadIdx.x;
    int orig = (lane < NB) ? bsum[lane] : 0;
    int v = orig;
#pragma unroll
    for (int d = 1; d < 64; d <<= 1) {
        int t = __shfl_up(v, d);
        if (lane >= d) v += t;
    }
    if (lane < NB) boff[lane] = v - orig;  // exclusive
}

__global__ void scan3_kernel(int* __restrict__ off, const int* __restrict__ boff, int N, int E) {
    int i = blockIdx.x * blockDim.x + threadIdx.x;
    if (i < N) off[i] += boff[i >> 11];
    if (i == 0) off[N] = E;
}

__global__ void fill_kernel(const int* __restrict__ src, const int* __restrict__ dst,
                            const float* __restrict__ w, int* __restrict__ cursor,
                            int* __restrict__ csr_src, float* __restrict__ csr_w, int E) {
    int i = blockIdx.x * blockDim.x + threadIdx.x;
    if (i < E) {
        int d = dst[i];
        int p = atomicAdd(&cursor[d], 1);
        csr_src[p] = src[i];
        csr_w[p] = w[i];
    }
}

// ---------------- dense GEMM: Out[M x NC] = X[M x 128] * W[128 x NC] ----------------
// lanes = cols (coalesced W read / C write); 8 rows per block, X reads wave-uniform (s_load)
template <int NC>
__global__ void gemm_kernel(const float* __restrict__ X, const float* __restrict__ W,
                            float* __restrict__ Out, int M) {
    const int col = threadIdx.x;  // 0..NC-1
    const int r0 = blockIdx.x * 8;
    float acc[8] = {0.f, 0.f, 0.f, 0.f, 0.f, 0.f, 0.f, 0.f};
    const float* xrow = X + (size_t)r0 * 128;
    for (int k = 0; k < 128; ++k) {
        float wv = W[k * NC + col];
#pragma unroll
        for (int r = 0; r < 8; ++r) acc[r] += xrow[r * 128 + k] * wv;
    }
#pragma unroll
    for (int r = 0; r < 8; ++r)
        if (r0 + r < M) Out[(size_t)(r0 + r) * NC + col] = acc[r];
}

// ---------------- SpMM (gather form): Out[n] = sum_e w_e * S[src_e]  ----------------
// one wave per destination node; edge loop wave-uniform; coalesced row gathers
template <int D>
__global__ void spmm_kernel(const float* __restrict__ S, const int* __restrict__ off,
                            const int* __restrict__ csr_src, const float* __restrict__ csr_w,
                            float* __restrict__ Out, int N) {
    const int node = blockIdx.x * (blockDim.x >> 6) + (threadIdx.x >> 6);
    const int lane = threadIdx.x & 63;
    if (node >= N) return;
    const int e0 = off[node];
    const int e1 = off[node + 1];
    float acc0 = 0.f, acc1 = 0.f;
    for (int e = e0; e < e1; ++e) {
        const int src = csr_src[e];   // wave-uniform
        const float w = csr_w[e];     // wave-uniform
        const float* row = S + (size_t)src * D;
        acc0 += w * row[lane];
        if (D == 128) acc1 += w * row[64 + lane];
    }
    Out[(size_t)node * D + lane] = acc0;
    if (D == 128) Out[(size_t)node * D + 64 + lane] = acc1;
}

// ---------------- bias + relu, in place, row width 128 ----------------
__global__ void bias_relu_kernel(float* __restrict__ A, const float* __restrict__ b, int total4) {
    int i = blockIdx.x * blockDim.x + threadIdx.x;
    if (i >= total4) return;
    float4 v = reinterpret_cast<float4*>(A)[i];
    int c = (i * 4) & 127;
    v.x = fmaxf(v.x + b[c + 0], 0.f);
    v.y = fmaxf(v.y + b[c + 1], 0.f);
    v.z = fmaxf(v.z + b[c + 2], 0.f);
    v.w = fmaxf(v.w + b[c + 3], 0.f);
    reinterpret_cast<float4*>(A)[i] = v;
}

// ---------------- log_softmax over 64 cols (one wave per row), bias fused ----------------
__global__ void logsoftmax_kernel(float* __restrict__ O, const float* __restrict__ b, int N) {
    const int node = blockIdx.x * (blockDim.x >> 6) + (threadIdx.x >> 6);
    const int lane = threadIdx.x & 63;
    if (node >= N) return;
    float v = O[(size_t)node * 64 + lane] + b[lane];
    float m = v;
#pragma unroll
    for (int d = 32; d >= 1; d >>= 1) m = fmaxf(m, __shfl_xor(m, d));
    float ex = __expf(v - m);
    float s = ex;
#pragma unroll
    for (int d = 32; d >= 1; d >>= 1) s += __shfl_xor(s, d);
    O[(size_t)node * 64 + lane] = (v - m) - __logf(s);
}

// ---------------- launch ----------------

extern "C" void kernel_launch(void* const* d_in, const int* in_sizes, int n_in,
                              void* d_out, int out_size, void* d_ws, size_t ws_size,
                              hipStream_t stream) {
    const float* x  = (const float*)d_in[0];
    const int* esrc = (const int*)d_in[1];
    const int* edst = (const int*)d_in[2];
    const float* ew = (const float*)d_in[3];
    const float* W1 = (const float*)d_in[4];
    const float* b1 = (const float*)d_in[5];
    const float* W2 = (const float*)d_in[6];
    const float* b2 = (const float*)d_in[7];
    const float* W3 = (const float*)d_in[8];
    const float* b3 = (const float*)d_in[9];

    const int N = in_sizes[0] / 128;  // 50000
    const int E = in_sizes[1];        // 800000

    // workspace carve (all 4-byte elements, 256B aligned)
    char* ws = (char*)d_ws;
    auto alloc = [&](size_t bytes) {
        char* p = ws;
        ws += (bytes + 255) & ~(size_t)255;
        return p;
    };
    int* counts   = (int*)alloc((size_t)N * 4);
    int* off      = (int*)alloc((size_t)(N + 1) * 4);
    int* cursor   = (int*)alloc((size_t)N * 4);
    int* bsum     = (int*)alloc(64 * 4);
    int* boff     = (int*)alloc(64 * 4);
    int* csr_src  = (int*)alloc((size_t)E * 4);
    float* csr_w  = (float*)alloc((size_t)E * 4);
    float* B0     = (float*)alloc((size_t)N * 128 * 4);
    float* B1     = (float*)alloc((size_t)N * 128 * 4);
    (void)ws_size;

    // ---- CSR build (per call; edges identical across layers) ----
    hipMemsetAsync(counts, 0, (size_t)N * 4, stream);
    hist_kernel<<<(E + 255) / 256, 256, 0, stream>>>(edst, counts, E);
    const int NB = (N + 2047) / 2048;  // 25
    scan1_kernel<<<NB, 256, 0, stream>>>(counts, off, bsum, N);
    scan2_kernel<<<1, 64, 0, stream>>>(bsum, boff, NB);
    scan3_kernel<<<(N + 255) / 256, 256, 0, stream>>>(off, boff, N, E);
    hipMemcpyAsync(cursor, off, (size_t)N * 4, hipMemcpyDeviceToDevice, stream);
    fill_kernel<<<(E + 255) / 256, 256, 0, stream>>>(esrc, edst, ew, cursor, csr_src, csr_w, E);

    // ---- layer 1: S = x @ W1 ; agg -> B1 ; relu(B1 + b1) ----
    gemm_kernel<128><<<(N + 7) / 8, 128, 0, stream>>>(x, W1, B0, N);
    spmm_kernel<128><<<(N + 3) / 4, 256, 0, stream>>>(B0, off, csr_src, csr_w, B1, N);
    bias_relu_kernel<<<((N * 32) + 255) / 256, 256, 0, stream>>>(B1, b1, N * 32);

    // ---- layer 2 ----
    gemm_kernel<128><<<(N + 7) / 8, 128, 0, stream>>>(B1, W2, B0, N);
    spmm_kernel<128><<<(N + 3) / 4, 256, 0, stream>>>(B0, off, csr_src, csr_w, B1, N);
    bias_relu_kernel<<<((N * 32) + 255) / 256, 256, 0, stream>>>(B1, b2, N * 32);

    // ---- layer 3: S = B1 @ W3 (64 cols) ; agg -> d_out ; log_softmax(+b3) ----
    gemm_kernel<64><<<(N + 7) / 8, 64, 0, stream>>>(B1, W3, B0, N);
    spmm_kernel<64><<<(N + 3) / 4, 256, 0, stream>>>(B0, off, csr_src, csr_w, (float*)d_out, N);
    logsoftmax_kernel<<<(N + 3) / 4, 256, 0, stream>>>((float*)d_out, b3, N);
}

// Round 2
// 374.907 us; speedup vs baseline: 1.4096x; 1.4096x over previous
//
#include <hip/hip_runtime.h>
#include <cstdint>
#include <cstddef>

// ---------------- CSR build ----------------

__global__ void hist_kernel(const int* __restrict__ dst, int* __restrict__ counts, int E) {
    int i = blockIdx.x * blockDim.x + threadIdx.x;
    if (i < E) atomicAdd(&counts[dst[i]], 1);
}

// 2048 elements per block (256 threads x 8), exclusive scan within block
__global__ void scan1_kernel(const int* __restrict__ counts, int* __restrict__ off,
                             int* __restrict__ bsum, int N) {
    __shared__ int sh[256];
    const int tid = threadIdx.x;
    const int base = blockIdx.x * 2048 + tid * 8;
    int v[8];
    int tsum = 0;
#pragma unroll
    for (int j = 0; j < 8; ++j) {
        int i = base + j;
        v[j] = (i < N) ? counts[i] : 0;
        tsum += v[j];
    }
    sh[tid] = tsum;
    __syncthreads();
    for (int d = 1; d < 256; d <<= 1) {
        int t = (tid >= d) ? sh[tid - d] : 0;
        __syncthreads();
        sh[tid] += t;
        __syncthreads();
    }
    int excl = sh[tid] - tsum;
    if (tid == 255) bsum[blockIdx.x] = sh[255];
    int run = excl;
#pragma unroll
    for (int j = 0; j < 8; ++j) {
        int i = base + j;
        if (i < N) off[i] = run;
        run += v[j];
    }
}

// single-wave scan of block sums (NB <= 64)
__global__ void scan2_kernel(const int* __restrict__ bsum, int* __restrict__ boff, int NB) {
    int lane = threadIdx.x;
    int orig = (lane < NB) ? bsum[lane] : 0;
    int v = orig;
#pragma unroll
    for (int d = 1; d < 64; d <<= 1) {
        int t = __shfl_up(v, d);
        if (lane >= d) v += t;
    }
    if (lane < NB) boff[lane] = v - orig;  // exclusive
}

__global__ void scan3_kernel(int* __restrict__ off, const int* __restrict__ boff, int N, int E) {
    int i = blockIdx.x * blockDim.x + threadIdx.x;
    if (i < N) off[i] += boff[i >> 11];
    if (i == 0) off[N] = E;
}

__global__ void fill_kernel(const int* __restrict__ src, const int* __restrict__ dst,
                            const float* __restrict__ w, int* __restrict__ cursor,
                            int* __restrict__ csr_src, float* __restrict__ csr_w, int E) {
    int i = blockIdx.x * blockDim.x + threadIdx.x;
    if (i < E) {
        int d = dst[i];
        int p = atomicAdd(&cursor[d], 1);
        csr_src[p] = src[i];
        csr_w[p] = w[i];
    }
}

// ---------------- dense GEMM: Out[M x NC] = X[M x 128] * W[128 x NC] ----------------
// lanes = cols (coalesced W read / C write); 8 rows per block.
// X reads are wave-uniform float4 -> s_load_dwordx4; W reads coalesced, 4 per group.
template <int NC>
__global__ void gemm_kernel(const float* __restrict__ X, const float* __restrict__ W,
                            float* __restrict__ Out, int M) {
    const int col = threadIdx.x;  // 0..NC-1
    const int r0 = blockIdx.x * 8;
    float acc[8] = {0.f, 0.f, 0.f, 0.f, 0.f, 0.f, 0.f, 0.f};
    const float4* xr = (const float4*)(X + (size_t)r0 * 128);  // 32 float4 per row
#pragma unroll 2
    for (int k4 = 0; k4 < 32; ++k4) {
        float w0 = W[(4 * k4 + 0) * NC + col];
        float w1 = W[(4 * k4 + 1) * NC + col];
        float w2 = W[(4 * k4 + 2) * NC + col];
        float w3 = W[(4 * k4 + 3) * NC + col];
#pragma unroll
        for (int r = 0; r < 8; ++r) {
            float4 xv = xr[(size_t)r * 32 + k4];  // uniform -> scalar load
            acc[r] = fmaf(xv.x, w0, acc[r]);
            acc[r] = fmaf(xv.y, w1, acc[r]);
            acc[r] = fmaf(xv.z, w2, acc[r]);
            acc[r] = fmaf(xv.w, w3, acc[r]);
        }
    }
#pragma unroll
    for (int r = 0; r < 8; ++r)
        if (r0 + r < M) Out[(size_t)(r0 + r) * NC + col] = acc[r];
}

// ---------------- SpMM (gather form) + fused epilogue ----------------
// one wave per destination node; edge loop wave-uniform (scalar loads);
// coalesced row gathers, float2-vectorized (D=128), unroll x4 for MLP.
// EPI: 0 = bias+relu (D=128), 1 = bias+log_softmax (D=64)
template <int D, int EPI>
__global__ void spmm_kernel(const float* __restrict__ S, const int* __restrict__ off,
                            const int* __restrict__ csr_src, const float* __restrict__ csr_w,
                            const float* __restrict__ bias, float* __restrict__ Out, int N) {
    const int node = blockIdx.x * (blockDim.x >> 6) + (threadIdx.x >> 6);
    const int lane = threadIdx.x & 63;
    if (node >= N) return;
    const int e0 = off[node];
    const int e1 = off[node + 1];

    if (D == 128) {
        const float2* S2 = (const float2*)S;  // 64 float2 per row
        float ax = 0.f, ay = 0.f;
        int e = e0;
        for (; e + 4 <= e1; e += 4) {
            int s0 = csr_src[e + 0], s1 = csr_src[e + 1];
            int s2 = csr_src[e + 2], s3 = csr_src[e + 3];
            float w0 = csr_w[e + 0], w1 = csr_w[e + 1];
            float w2 = csr_w[e + 2], w3 = csr_w[e + 3];
            float2 v0 = S2[(size_t)s0 * 64 + lane];
            float2 v1 = S2[(size_t)s1 * 64 + lane];
            float2 v2 = S2[(size_t)s2 * 64 + lane];
            float2 v3 = S2[(size_t)s3 * 64 + lane];
            ax = fmaf(w0, v0.x, ax); ay = fmaf(w0, v0.y, ay);
            ax = fmaf(w1, v1.x, ax); ay = fmaf(w1, v1.y, ay);
            ax = fmaf(w2, v2.x, ax); ay = fmaf(w2, v2.y, ay);
            ax = fmaf(w3, v3.x, ax); ay = fmaf(w3, v3.y, ay);
        }
        for (; e < e1; ++e) {
            int s = csr_src[e];
            float w = csr_w[e];
            float2 v = S2[(size_t)s * 64 + lane];
            ax = fmaf(w, v.x, ax); ay = fmaf(w, v.y, ay);
        }
        // epilogue: bias + relu
        ax = fmaxf(ax + bias[2 * lane + 0], 0.f);
        ay = fmaxf(ay + bias[2 * lane + 1], 0.f);
        float2 o; o.x = ax; o.y = ay;
        ((float2*)Out)[(size_t)node * 64 + lane] = o;
    } else {
        // D == 64: one float per lane
        float acc = 0.f;
        int e = e0;
        for (; e + 4 <= e1; e += 4) {
            int s0 = csr_src[e + 0], s1 = csr_src[e + 1];
            int s2 = csr_src[e + 2], s3 = csr_src[e + 3];
            float w0 = csr_w[e + 0], w1 = csr_w[e + 1];
            float w2 = csr_w[e + 2], w3 = csr_w[e + 3];
            float v0 = S[(size_t)s0 * 64 + lane];
            float v1 = S[(size_t)s1 * 64 + lane];
            float v2 = S[(size_t)s2 * 64 + lane];
            float v3 = S[(size_t)s3 * 64 + lane];
            acc = fmaf(w0, v0, acc);
            acc = fmaf(w1, v1, acc);
            acc = fmaf(w2, v2, acc);
            acc = fmaf(w3, v3, acc);
        }
        for (; e < e1; ++e) {
            acc = fmaf(csr_w[e], S[(size_t)csr_src[e] * 64 + lane], acc);
        }
        if (EPI == 1) {
            // bias + log_softmax over the 64 cols held by this wave
            float v = acc + bias[lane];
            float m = v;
#pragma unroll
            for (int d = 32; d >= 1; d >>= 1) m = fmaxf(m, __shfl_xor(m, d));
            float ex = __expf(v - m);
            float s = ex;
#pragma unroll
            for (int d = 32; d >= 1; d >>= 1) s += __shfl_xor(s, d);
            Out[(size_t)node * 64 + lane] = (v - m) - __logf(s);
        } else {
            Out[(size_t)node * 64 + lane] = fmaxf(acc + bias[lane], 0.f);
        }
    }
}

// ---------------- launch ----------------

extern "C" void kernel_launch(void* const* d_in, const int* in_sizes, int n_in,
                              void* d_out, int out_size, void* d_ws, size_t ws_size,
                              hipStream_t stream) {
    const float* x  = (const float*)d_in[0];
    const int* esrc = (const int*)d_in[1];
    const int* edst = (const int*)d_in[2];
    const float* ew = (const float*)d_in[3];
    const float* W1 = (const float*)d_in[4];
    const float* b1 = (const float*)d_in[5];
    const float* W2 = (const float*)d_in[6];
    const float* b2 = (const float*)d_in[7];
    const float* W3 = (const float*)d_in[8];
    const float* b3 = (const float*)d_in[9];

    const int N = in_sizes[0] / 128;  // 50000
    const int E = in_sizes[1];        // 800000

    // workspace carve (all 4-byte elements, 256B aligned)
    char* ws = (char*)d_ws;
    auto alloc = [&](size_t bytes) {
        char* p = ws;
        ws += (bytes + 255) & ~(size_t)255;
        return p;
    };
    int* counts   = (int*)alloc((size_t)N * 4);
    int* off      = (int*)alloc((size_t)(N + 1) * 4);
    int* cursor   = (int*)alloc((size_t)N * 4);
    int* bsum     = (int*)alloc(64 * 4);
    int* boff     = (int*)alloc(64 * 4);
    int* csr_src  = (int*)alloc((size_t)E * 4);
    float* csr_w  = (float*)alloc((size_t)E * 4);
    float* B0     = (float*)alloc((size_t)N * 128 * 4);
    float* B1     = (float*)alloc((size_t)N * 128 * 4);
    (void)ws_size;

    // ---- CSR build (per call; edges identical across layers) ----
    hipMemsetAsync(counts, 0, (size_t)N * 4, stream);
    hist_kernel<<<(E + 255) / 256, 256, 0, stream>>>(edst, counts, E);
    const int NB = (N + 2047) / 2048;  // 25
    scan1_kernel<<<NB, 256, 0, stream>>>(counts, off, bsum, N);
    scan2_kernel<<<1, 64, 0, stream>>>(bsum, boff, NB);
    scan3_kernel<<<(N + 255) / 256, 256, 0, stream>>>(off, boff, N, E);
    hipMemcpyAsync(cursor, off, (size_t)N * 4, hipMemcpyDeviceToDevice, stream);
    fill_kernel<<<(E + 255) / 256, 256, 0, stream>>>(esrc, edst, ew, cursor, csr_src, csr_w, E);

    // ---- layer 1: S = x @ W1 ; agg+bias+relu -> B1 ----
    gemm_kernel<128><<<(N + 7) / 8, 128, 0, stream>>>(x, W1, B0, N);
    spmm_kernel<128, 0><<<(N + 3) / 4, 256, 0, stream>>>(B0, off, csr_src, csr_w, b1, B1, N);

    // ---- layer 2 ----
    gemm_kernel<128><<<(N + 7) / 8, 128, 0, stream>>>(B1, W2, B0, N);
    spmm_kernel<128, 0><<<(N + 3) / 4, 256, 0, stream>>>(B0, off, csr_src, csr_w, b2, B1, N);

    // ---- layer 3: S = B1 @ W3 (64 cols) ; agg+bias+log_softmax -> d_out ----
    gemm_kernel<64><<<(N + 7) / 8, 64, 0, stream>>>(B1, W3, B0, N);
    spmm_kernel<64, 1><<<(N + 3) / 4, 256, 0, stream>>>(B0, off, csr_src, csr_w, b3, (float*)d_out, N);
}

// Round 3
// 260.647 us; speedup vs baseline: 2.0276x; 1.4384x over previous
//
#include <hip/hip_runtime.h>
#include <cstdint>
#include <cstddef>

typedef __attribute__((ext_vector_type(8))) short short8v;
typedef __attribute__((ext_vector_type(4))) float f32x4;

__device__ inline uint bf16_rne(float f) {
    uint u = __float_as_uint(f);
    return (u + 0x7fffu + ((u >> 16) & 1u)) >> 16;
}
__device__ inline float bf16lo_to_f(uint v) { return __uint_as_float(v << 16); }
__device__ inline float bf16hi_to_f(uint v) { return __uint_as_float(v & 0xffff0000u); }

// ---------------- CSR build ----------------

__global__ void hist_kernel(const int* __restrict__ dst, int* __restrict__ counts, int E) {
    int i = blockIdx.x * blockDim.x + threadIdx.x;
    if (i < E) atomicAdd(&counts[dst[i]], 1);
}

// 2048 elements per block (256 threads x 8), exclusive scan within block
__global__ void scan1_kernel(const int* __restrict__ counts, int* __restrict__ off,
                             int* __restrict__ bsum, int N) {
    __shared__ int sh[256];
    const int tid = threadIdx.x;
    const int base = blockIdx.x * 2048 + tid * 8;
    int v[8];
    int tsum = 0;
#pragma unroll
    for (int j = 0; j < 8; ++j) {
        int i = base + j;
        v[j] = (i < N) ? counts[i] : 0;
        tsum += v[j];
    }
    sh[tid] = tsum;
    __syncthreads();
    for (int d = 1; d < 256; d <<= 1) {
        int t = (tid >= d) ? sh[tid - d] : 0;
        __syncthreads();
        sh[tid] += t;
        __syncthreads();
    }
    int excl = sh[tid] - tsum;
    if (tid == 255) bsum[blockIdx.x] = sh[255];
    int run = excl;
#pragma unroll
    for (int j = 0; j < 8; ++j) {
        int i = base + j;
        if (i < N) off[i] = run;
        run += v[j];
    }
}

// single-wave scan of block sums (NB <= 64)
__global__ void scan2_kernel(const int* __restrict__ bsum, int* __restrict__ boff, int NB) {
    int lane = threadIdx.x;
    int orig = (lane < NB) ? bsum[lane] : 0;
    int v = orig;
#pragma unroll
    for (int d = 1; d < 64; d <<= 1) {
        int t = __shfl_up(v, d);
        if (lane >= d) v += t;
    }
    if (lane < NB) boff[lane] = v - orig;  // exclusive
}

// adds block offsets AND writes the fill cursor (saves a D2D copy)
__global__ void scan3_kernel(int* __restrict__ off, int* __restrict__ cursor,
                             const int* __restrict__ boff, int N, int E) {
    int i = blockIdx.x * blockDim.x + threadIdx.x;
    if (i < N) {
        int v = off[i] + boff[i >> 11];
        off[i] = v;
        cursor[i] = v;
    }
    if (i == 0) off[N] = E;
}

// packed (src, weight-bits) single 8B store per edge: one write-allocate line, not two
__global__ void fill_kernel(const int* __restrict__ src, const int* __restrict__ dst,
                            const float* __restrict__ w, int* __restrict__ cursor,
                            int2* __restrict__ csr, int E) {
    int i = blockIdx.x * blockDim.x + threadIdx.x;
    if (i < E) {
        int d = dst[i];
        int p = atomicAdd(&cursor[d], 1);
        csr[p] = make_int2(src[i], __float_as_int(w[i]));
    }
}

// ---------------- casts / weight packing ----------------

// f32 -> bf16, 4 elems per thread
__global__ void cast_x_kernel(const float* __restrict__ X, ushort* __restrict__ Xb, int total4) {
    int i = blockIdx.x * blockDim.x + threadIdx.x;
    if (i >= total4) return;
    float4 v = reinterpret_cast<const float4*>(X)[i];
    uint2 o;
    o.x = (bf16_rne(v.y) << 16) | bf16_rne(v.x);
    o.y = (bf16_rne(v.w) << 16) | bf16_rne(v.z);
    reinterpret_cast<uint2*>(Xb)[i] = o;
}

// pack W[128 x NC] f32 into MFMA B-fragment order (bf16):
// Wp[((c*4+kb)*64 + l)*8 + j] = W[(kb*32 + (l>>4)*8 + j)*NC + c*16 + (l&15)]
__global__ void pack_w_kernel(const float* __restrict__ W, ushort* __restrict__ Wp, int NC) {
    int i = blockIdx.x * blockDim.x + threadIdx.x;
    if (i >= 128 * NC) return;
    int j = i & 7, l = (i >> 3) & 63, kb = (i >> 9) & 3, c = i >> 11;
    int row = kb * 32 + ((l >> 4) & 3) * 8 + j;
    int col = c * 16 + (l & 15);
    Wp[i] = (ushort)bf16_rne(W[row * NC + col]);
}

// ---------------- MFMA GEMM: S[M x NC] (bf16) = Xb[M x 128] (bf16) @ Wp ----------------
// 256 threads = 4 waves; 64 rows per block (16 per wave); W staged in LDS.
template <int NC>
__global__ __launch_bounds__(256) void gemm_mfma(const ushort* __restrict__ Xb,
                                                 const ushort* __restrict__ Wp,
                                                 ushort* __restrict__ Out, int M) {
    __shared__ ushort WL[128 * NC];
    const int t = threadIdx.x;
    // stage packed W (128*NC*2 bytes) into LDS
    {
        const uint4* src = (const uint4*)Wp;
        uint4* dst = (uint4*)WL;
#pragma unroll
        for (int i = 0; i < NC / 16; ++i) dst[t + i * 256] = src[t + i * 256];
    }
    __syncthreads();

    const int wave = t >> 6, l = t & 63;
    const int lr = l & 15, lh = l >> 4;
    const int rowbase = blockIdx.x * 64 + wave * 16;

    // A fragments: lane holds a[lr][kb*32 + lh*8 + j], contiguous 16B
    short8v a[4];
    const ushort* arow = Xb + (size_t)(rowbase + lr) * 128 + lh * 8;
#pragma unroll
    for (int kb = 0; kb < 4; ++kb) a[kb] = *(const short8v*)(arow + kb * 32);

    f32x4 acc[NC / 16];
#pragma unroll
    for (int c = 0; c < NC / 16; ++c) acc[c] = (f32x4){0.f, 0.f, 0.f, 0.f};

#pragma unroll
    for (int c = 0; c < NC / 16; ++c)
#pragma unroll
        for (int kb = 0; kb < 4; ++kb) {
            short8v b = *(const short8v*)(WL + ((c * 4 + kb) * 64 + l) * 8);
            acc[c] = __builtin_amdgcn_mfma_f32_16x16x32_bf16(a[kb], b, acc[c], 0, 0, 0);
        }

#pragma unroll
    for (int c = 0; c < NC / 16; ++c)
#pragma unroll
        for (int i = 0; i < 4; ++i) {
            int row = rowbase + lh * 4 + i;
            if (row < M) Out[(size_t)row * NC + c * 16 + lr] = (ushort)bf16_rne(acc[c][i]);
        }
}

// ---------------- SpMM (gather) D=128 bf16 + bias+relu -> bf16 ----------------
__global__ void spmm128_kernel(const uint* __restrict__ S, const int* __restrict__ off,
                               const int2* __restrict__ csr, const float* __restrict__ bias,
                               uint* __restrict__ Out, int N) {
    const int node = blockIdx.x * (blockDim.x >> 6) + (threadIdx.x >> 6);
    const int lane = threadIdx.x & 63;
    if (node >= N) return;
    const int e0 = off[node];
    const int e1 = off[node + 1];
    float ax = 0.f, ay = 0.f;
    int e = e0;
    for (; e + 4 <= e1; e += 4) {
        int2 E0 = csr[e + 0], E1 = csr[e + 1], E2 = csr[e + 2], E3 = csr[e + 3];
        uint v0 = S[(size_t)E0.x * 64 + lane];
        uint v1 = S[(size_t)E1.x * 64 + lane];
        uint v2 = S[(size_t)E2.x * 64 + lane];
        uint v3 = S[(size_t)E3.x * 64 + lane];
        float w0 = __int_as_float(E0.y), w1 = __int_as_float(E1.y);
        float w2 = __int_as_float(E2.y), w3 = __int_as_float(E3.y);
        ax = fmaf(w0, bf16lo_to_f(v0), ax); ay = fmaf(w0, bf16hi_to_f(v0), ay);
        ax = fmaf(w1, bf16lo_to_f(v1), ax); ay = fmaf(w1, bf16hi_to_f(v1), ay);
        ax = fmaf(w2, bf16lo_to_f(v2), ax); ay = fmaf(w2, bf16hi_to_f(v2), ay);
        ax = fmaf(w3, bf16lo_to_f(v3), ax); ay = fmaf(w3, bf16hi_to_f(v3), ay);
    }
    for (; e < e1; ++e) {
        int2 E = csr[e];
        uint v = S[(size_t)E.x * 64 + lane];
        float w = __int_as_float(E.y);
        ax = fmaf(w, bf16lo_to_f(v), ax);
        ay = fmaf(w, bf16hi_to_f(v), ay);
    }
    ax = fmaxf(ax + bias[2 * lane + 0], 0.f);
    ay = fmaxf(ay + bias[2 * lane + 1], 0.f);
    Out[(size_t)node * 64 + lane] = (bf16_rne(ay) << 16) | bf16_rne(ax);
}

// ---------------- SpMM D=64 bf16 + bias + log_softmax -> f32 ----------------
__global__ void spmm64_kernel(const ushort* __restrict__ S, const int* __restrict__ off,
                              const int2* __restrict__ csr, const float* __restrict__ bias,
                              float* __restrict__ Out, int N) {
    const int node = blockIdx.x * (blockDim.x >> 6) + (threadIdx.x >> 6);
    const int lane = threadIdx.x & 63;
    if (node >= N) return;
    const int e0 = off[node];
    const int e1 = off[node + 1];
    float acc = 0.f;
    int e = e0;
    for (; e + 4 <= e1; e += 4) {
        int2 E0 = csr[e + 0], E1 = csr[e + 1], E2 = csr[e + 2], E3 = csr[e + 3];
        float v0 = bf16lo_to_f((uint)S[(size_t)E0.x * 64 + lane]);
        float v1 = bf16lo_to_f((uint)S[(size_t)E1.x * 64 + lane]);
        float v2 = bf16lo_to_f((uint)S[(size_t)E2.x * 64 + lane]);
        float v3 = bf16lo_to_f((uint)S[(size_t)E3.x * 64 + lane]);
        acc = fmaf(__int_as_float(E0.y), v0, acc);
        acc = fmaf(__int_as_float(E1.y), v1, acc);
        acc = fmaf(__int_as_float(E2.y), v2, acc);
        acc = fmaf(__int_as_float(E3.y), v3, acc);
    }
    for (; e < e1; ++e) {
        int2 E = csr[e];
        acc = fmaf(__int_as_float(E.y), bf16lo_to_f((uint)S[(size_t)E.x * 64 + lane]), acc);
    }
    float v = acc + bias[lane];
    float m = v;
#pragma unroll
    for (int d = 32; d >= 1; d >>= 1) m = fmaxf(m, __shfl_xor(m, d));
    float ex = __expf(v - m);
    float s = ex;
#pragma unroll
    for (int d = 32; d >= 1; d >>= 1) s += __shfl_xor(s, d);
    Out[(size_t)node * 64 + lane] = (v - m) - __logf(s);
}

// ---------------- launch ----------------

extern "C" void kernel_launch(void* const* d_in, const int* in_sizes, int n_in,
                              void* d_out, int out_size, void* d_ws, size_t ws_size,
                              hipStream_t stream) {
    const float* x  = (const float*)d_in[0];
    const int* esrc = (const int*)d_in[1];
    const int* edst = (const int*)d_in[2];
    const float* ew = (const float*)d_in[3];
    const float* W1 = (const float*)d_in[4];
    const float* b1 = (const float*)d_in[5];
    const float* W2 = (const float*)d_in[6];
    const float* b2 = (const float*)d_in[7];
    const float* W3 = (const float*)d_in[8];
    const float* b3 = (const float*)d_in[9];

    const int N = in_sizes[0] / 128;  // 50000
    const int E = in_sizes[1];        // 800000

    // workspace carve (256B aligned)
    char* ws = (char*)d_ws;
    auto alloc = [&](size_t bytes) {
        char* p = ws;
        ws += (bytes + 255) & ~(size_t)255;
        return p;
    };
    int* counts  = (int*)alloc((size_t)N * 4);
    int* off     = (int*)alloc((size_t)(N + 1) * 4);
    int* cursor  = (int*)alloc((size_t)N * 4);
    int* bsum    = (int*)alloc(64 * 4);
    int* boff    = (int*)alloc(64 * 4);
    int2* csr    = (int2*)alloc((size_t)E * 8);
    ushort* Xb   = (ushort*)alloc((size_t)N * 128 * 2);
    ushort* Sb   = (ushort*)alloc((size_t)N * 128 * 2);
    ushort* Hb   = (ushort*)alloc((size_t)N * 128 * 2);
    ushort* Wp1  = (ushort*)alloc(128 * 128 * 2);
    ushort* Wp2  = (ushort*)alloc(128 * 128 * 2);
    ushort* Wp3  = (ushort*)alloc(128 * 64 * 2);
    (void)ws_size;

    // ---- CSR build ----
    hipMemsetAsync(counts, 0, (size_t)N * 4, stream);
    hist_kernel<<<(E + 255) / 256, 256, 0, stream>>>(edst, counts, E);
    const int NB = (N + 2047) / 2048;  // 25
    scan1_kernel<<<NB, 256, 0, stream>>>(counts, off, bsum, N);
    scan2_kernel<<<1, 64, 0, stream>>>(bsum, boff, NB);
    scan3_kernel<<<(N + 255) / 256, 256, 0, stream>>>(off, cursor, boff, N, E);
    fill_kernel<<<(E + 255) / 256, 256, 0, stream>>>(esrc, edst, ew, cursor, csr, E);

    // ---- casts / weight packing ----
    cast_x_kernel<<<((N * 32) + 255) / 256, 256, 0, stream>>>(x, Xb, N * 32);
    pack_w_kernel<<<(128 * 128 + 255) / 256, 256, 0, stream>>>(W1, Wp1, 128);
    pack_w_kernel<<<(128 * 128 + 255) / 256, 256, 0, stream>>>(W2, Wp2, 128);
    pack_w_kernel<<<(128 * 64 + 255) / 256, 256, 0, stream>>>(W3, Wp3, 64);

    const int gemm_blocks = (N + 63) / 64;

    // ---- layer 1 ----
    gemm_mfma<128><<<gemm_blocks, 256, 0, stream>>>(Xb, Wp1, Sb, N);
    spmm128_kernel<<<(N + 3) / 4, 256, 0, stream>>>((const uint*)Sb, off, csr, b1, (uint*)Hb, N);

    // ---- layer 2 ----
    gemm_mfma<128><<<gemm_blocks, 256, 0, stream>>>(Hb, Wp2, Sb, N);
    spmm128_kernel<<<(N + 3) / 4, 256, 0, stream>>>((const uint*)Sb, off, csr, b2, (uint*)Hb, N);

    // ---- layer 3 ----
    gemm_mfma<64><<<gemm_blocks, 256, 0, stream>>>(Hb, Wp3, Sb, N);
    spmm64_kernel<<<(N + 3) / 4, 256, 0, stream>>>(Sb, off, csr, b3, (float*)d_out, N);
}

// Round 4
// 243.471 us; speedup vs baseline: 2.1706x; 1.0705x over previous
//
#include <hip/hip_runtime.h>
#include <cstdint>
#include <cstddef>

typedef __attribute__((ext_vector_type(8))) short short8v;
typedef __attribute__((ext_vector_type(4))) float f32x4;

__device__ inline uint bf16_rne(float f) {
    uint u = __float_as_uint(f);
    return (u + 0x7fffu + ((u >> 16) & 1u)) >> 16;
}
__device__ inline float bf16lo_to_f(uint v) { return __uint_as_float(v << 16); }
__device__ inline float bf16hi_to_f(uint v) { return __uint_as_float(v & 0xffff0000u); }

// ---------------- init: zero counts + pack all three weight matrices ----------------
// pack W[128 x NC] f32 into MFMA B-fragment order (bf16):
// Wp[((c*4+kb)*64 + l)*8 + j] = W[(kb*32 + (l>>4)*8 + j)*NC + c*16 + (l&15)]
__device__ inline void pack_one(const float* __restrict__ W, ushort* __restrict__ Wp,
                                int NC, int i) {
    int j = i & 7, l = (i >> 3) & 63, kb = (i >> 9) & 3, c = i >> 11;
    int row = kb * 32 + ((l >> 4) & 3) * 8 + j;
    int col = c * 16 + (l & 15);
    Wp[i] = (ushort)bf16_rne(W[row * NC + col]);
}

__global__ void init_kernel(int* __restrict__ counts, int N,
                            const float* __restrict__ W1, ushort* __restrict__ Wp1,
                            const float* __restrict__ W2, ushort* __restrict__ Wp2,
                            const float* __restrict__ W3, ushort* __restrict__ Wp3) {
    int i = blockIdx.x * blockDim.x + threadIdx.x;
    if (i < N) counts[i] = 0;
    int zblocks = (N + 255) >> 8;
    int p = i - zblocks * 256;
    if (p >= 0) {
        if (p < 16384) pack_one(W1, Wp1, 128, p);
        else if (p < 32768) pack_one(W2, Wp2, 128, p - 16384);
        else if (p < 40960) pack_one(W3, Wp3, 64, p - 32768);
    }
}

// ---------------- CSR build ----------------

__global__ void hist_kernel(const int* __restrict__ dst, int* __restrict__ counts, int E) {
    int i = blockIdx.x * blockDim.x + threadIdx.x;
    if (i < E) atomicAdd(&counts[dst[i]], 1);
}

// 2048 elements per block (256 threads x 8), exclusive scan within block
__global__ void scan1_kernel(const int* __restrict__ counts, int* __restrict__ off,
                             int* __restrict__ bsum, int N) {
    __shared__ int sh[256];
    const int tid = threadIdx.x;
    const int base = blockIdx.x * 2048 + tid * 8;
    int v[8];
    int tsum = 0;
#pragma unroll
    for (int j = 0; j < 8; ++j) {
        int i = base + j;
        v[j] = (i < N) ? counts[i] : 0;
        tsum += v[j];
    }
    sh[tid] = tsum;
    __syncthreads();
    for (int d = 1; d < 256; d <<= 1) {
        int t = (tid >= d) ? sh[tid - d] : 0;
        __syncthreads();
        sh[tid] += t;
        __syncthreads();
    }
    int excl = sh[tid] - tsum;
    if (tid == 255) bsum[blockIdx.x] = sh[255];
    int run = excl;
#pragma unroll
    for (int j = 0; j < 8; ++j) {
        int i = base + j;
        if (i < N) off[i] = run;
        run += v[j];
    }
}

// single-wave scan of block sums (NB <= 64)
__global__ void scan2_kernel(const int* __restrict__ bsum, int* __restrict__ boff, int NB) {
    int lane = threadIdx.x;
    int orig = (lane < NB) ? bsum[lane] : 0;
    int v = orig;
#pragma unroll
    for (int d = 1; d < 64; d <<= 1) {
        int t = __shfl_up(v, d);
        if (lane >= d) v += t;
    }
    if (lane < NB) boff[lane] = v - orig;  // exclusive
}

// adds block offsets AND writes the fill cursor
__global__ void scan3_kernel(int* __restrict__ off, int* __restrict__ cursor,
                             const int* __restrict__ boff, int N, int E) {
    int i = blockIdx.x * blockDim.x + threadIdx.x;
    if (i < N) {
        int v = off[i] + boff[i >> 11];
        off[i] = v;
        cursor[i] = v;
    }
    if (i == 0) off[N] = E;
}

// packed edge: (bf16(w) << 16) | src  -- 4 bytes per edge
__global__ void fill_kernel(const int* __restrict__ src, const int* __restrict__ dst,
                            const float* __restrict__ w, int* __restrict__ cursor,
                            uint* __restrict__ csr, int E) {
    int i = blockIdx.x * blockDim.x + threadIdx.x;
    if (i < E) {
        int d = dst[i];
        int p = atomicAdd(&cursor[d], 1);
        csr[p] = (bf16_rne(w[i]) << 16) | (uint)src[i];
    }
}

// ---------------- MFMA GEMM: S[M x NC] (bf16) = X[M x 128] @ Wp ----------------
// 256 threads = 4 waves; 64 rows per block (16 per wave); W staged in LDS.
// F32IN: input is f32 (layer 1, cast fused); else bf16.
template <int NC, bool F32IN>
__global__ __launch_bounds__(256) void gemm_mfma(const void* __restrict__ Xin,
                                                 const ushort* __restrict__ Wp,
                                                 ushort* __restrict__ Out, int M) {
    __shared__ ushort WL[128 * NC];
    const int t = threadIdx.x;
    {
        const uint4* srcp = (const uint4*)Wp;
        uint4* dstp = (uint4*)WL;
#pragma unroll
        for (int i = 0; i < NC / 16; ++i) dstp[t + i * 256] = srcp[t + i * 256];
    }
    __syncthreads();

    const int wave = t >> 6, l = t & 63;
    const int lr = l & 15, lh = l >> 4;
    const int rowbase = blockIdx.x * 64 + wave * 16;
    const int arow_idx = min(rowbase + lr, M - 1);  // clamp: avoid OOB read on tail block

    short8v a[4];
    if (F32IN) {
        const float* arow = (const float*)Xin + (size_t)arow_idx * 128 + lh * 8;
#pragma unroll
        for (int kb = 0; kb < 4; ++kb) {
            float4 u = *(const float4*)(arow + kb * 32);
            float4 v = *(const float4*)(arow + kb * 32 + 4);
            short8v av;
            av[0] = (short)bf16_rne(u.x); av[1] = (short)bf16_rne(u.y);
            av[2] = (short)bf16_rne(u.z); av[3] = (short)bf16_rne(u.w);
            av[4] = (short)bf16_rne(v.x); av[5] = (short)bf16_rne(v.y);
            av[6] = (short)bf16_rne(v.z); av[7] = (short)bf16_rne(v.w);
            a[kb] = av;
        }
    } else {
        const ushort* arow = (const ushort*)Xin + (size_t)arow_idx * 128 + lh * 8;
#pragma unroll
        for (int kb = 0; kb < 4; ++kb) a[kb] = *(const short8v*)(arow + kb * 32);
    }

    f32x4 acc[NC / 16];
#pragma unroll
    for (int c = 0; c < NC / 16; ++c) acc[c] = (f32x4){0.f, 0.f, 0.f, 0.f};

#pragma unroll
    for (int c = 0; c < NC / 16; ++c)
#pragma unroll
        for (int kb = 0; kb < 4; ++kb) {
            short8v b = *(const short8v*)(WL + ((c * 4 + kb) * 64 + l) * 8);
            acc[c] = __builtin_amdgcn_mfma_f32_16x16x32_bf16(a[kb], b, acc[c], 0, 0, 0);
        }

#pragma unroll
    for (int c = 0; c < NC / 16; ++c)
#pragma unroll
        for (int i = 0; i < 4; ++i) {
            int row = rowbase + lh * 4 + i;
            if (row < M) Out[(size_t)row * NC + c * 16 + lr] = (ushort)bf16_rne(acc[c][i]);
        }
}

// ---------------- SpMM (gather) D=128 bf16 + bias+relu -> bf16 ----------------
__global__ void spmm128_kernel(const uint* __restrict__ S, const int* __restrict__ off,
                               const uint* __restrict__ csr, const float* __restrict__ bias,
                               uint* __restrict__ Out, int N) {
    const int node = blockIdx.x * (blockDim.x >> 6) + (threadIdx.x >> 6);
    const int lane = threadIdx.x & 63;
    if (node >= N) return;
    const int e0 = off[node];
    const int e1 = off[node + 1];
    float ax = 0.f, ay = 0.f;
    int e = e0;

#define EDGE128(pk)                                                  \
    {                                                                \
        uint _p = (pk);                                              \
        float _w = __uint_as_float(_p & 0xffff0000u);                \
        uint _v = S[(size_t)(_p & 0xffffu) * 64 + lane];             \
        ax = fmaf(_w, bf16lo_to_f(_v), ax);                          \
        ay = fmaf(_w, bf16hi_to_f(_v), ay);                          \
    }

    while (e < e1 && (e & 3)) { EDGE128(csr[e]); ++e; }
    for (; e + 8 <= e1; e += 8) {
        uint4 c0 = *(const uint4*)(csr + e);
        uint4 c1 = *(const uint4*)(csr + e + 4);
        EDGE128(c0.x); EDGE128(c0.y); EDGE128(c0.z); EDGE128(c0.w);
        EDGE128(c1.x); EDGE128(c1.y); EDGE128(c1.z); EDGE128(c1.w);
    }
    for (; e + 4 <= e1; e += 4) {
        uint4 c0 = *(const uint4*)(csr + e);
        EDGE128(c0.x); EDGE128(c0.y); EDGE128(c0.z); EDGE128(c0.w);
    }
    for (; e < e1; ++e) EDGE128(csr[e]);
#undef EDGE128

    float2 bv = ((const float2*)bias)[lane];
    ax = fmaxf(ax + bv.x, 0.f);
    ay = fmaxf(ay + bv.y, 0.f);
    Out[(size_t)node * 64 + lane] = (bf16_rne(ay) << 16) | bf16_rne(ax);
}

// ---------------- SpMM D=64 bf16 + bias + log_softmax -> f32 ----------------
__global__ void spmm64_kernel(const ushort* __restrict__ S, const int* __restrict__ off,
                              const uint* __restrict__ csr, const float* __restrict__ bias,
                              float* __restrict__ Out, int N) {
    const int node = blockIdx.x * (blockDim.x >> 6) + (threadIdx.x >> 6);
    const int lane = threadIdx.x & 63;
    if (node >= N) return;
    const int e0 = off[node];
    const int e1 = off[node + 1];
    float acc = 0.f;
    int e = e0;

#define EDGE64(pk)                                                              \
    {                                                                           \
        uint _p = (pk);                                                         \
        float _w = __uint_as_float(_p & 0xffff0000u);                           \
        acc = fmaf(_w, bf16lo_to_f((uint)S[(size_t)(_p & 0xffffu) * 64 + lane]), acc); \
    }

    while (e < e1 && (e & 3)) { EDGE64(csr[e]); ++e; }
    for (; e + 8 <= e1; e += 8) {
        uint4 c0 = *(const uint4*)(csr + e);
        uint4 c1 = *(const uint4*)(csr + e + 4);
        EDGE64(c0.x); EDGE64(c0.y); EDGE64(c0.z); EDGE64(c0.w);
        EDGE64(c1.x); EDGE64(c1.y); EDGE64(c1.z); EDGE64(c1.w);
    }
    for (; e + 4 <= e1; e += 4) {
        uint4 c0 = *(const uint4*)(csr + e);
        EDGE64(c0.x); EDGE64(c0.y); EDGE64(c0.z); EDGE64(c0.w);
    }
    for (; e < e1; ++e) EDGE64(csr[e]);
#undef EDGE64

    float v = acc + bias[lane];
    float m = v;
#pragma unroll
    for (int d = 32; d >= 1; d >>= 1) m = fmaxf(m, __shfl_xor(m, d));
    float ex = __expf(v - m);
    float s = ex;
#pragma unroll
    for (int d = 32; d >= 1; d >>= 1) s += __shfl_xor(s, d);
    Out[(size_t)node * 64 + lane] = (v - m) - __logf(s);
}

// ---------------- launch ----------------

extern "C" void kernel_launch(void* const* d_in, const int* in_sizes, int n_in,
                              void* d_out, int out_size, void* d_ws, size_t ws_size,
                              hipStream_t stream) {
    const float* x  = (const float*)d_in[0];
    const int* esrc = (const int*)d_in[1];
    const int* edst = (const int*)d_in[2];
    const float* ew = (const float*)d_in[3];
    const float* W1 = (const float*)d_in[4];
    const float* b1 = (const float*)d_in[5];
    const float* W2 = (const float*)d_in[6];
    const float* b2 = (const float*)d_in[7];
    const float* W3 = (const float*)d_in[8];
    const float* b3 = (const float*)d_in[9];

    const int N = in_sizes[0] / 128;  // 50000
    const int E = in_sizes[1];        // 800000

    // workspace carve (256B aligned)
    char* ws = (char*)d_ws;
    auto alloc = [&](size_t bytes) {
        char* p = ws;
        ws += (bytes + 255) & ~(size_t)255;
        return p;
    };
    int* counts  = (int*)alloc((size_t)N * 4);
    int* off     = (int*)alloc((size_t)(N + 1) * 4);
    int* cursor  = (int*)alloc((size_t)N * 4);
    int* bsum    = (int*)alloc(64 * 4);
    int* boff    = (int*)alloc(64 * 4);
    uint* csr    = (uint*)alloc((size_t)E * 4);
    ushort* Sb   = (ushort*)alloc((size_t)N * 128 * 2);
    ushort* Hb   = (ushort*)alloc((size_t)N * 128 * 2);
    ushort* Wp1  = (ushort*)alloc(128 * 128 * 2);
    ushort* Wp2  = (ushort*)alloc(128 * 128 * 2);
    ushort* Wp3  = (ushort*)alloc(128 * 64 * 2);
    (void)ws_size;

    // ---- init (zero counts + pack weights) ----
    const int zblocks = (N + 255) / 256;
    init_kernel<<<zblocks + (40960 + 255) / 256, 256, 0, stream>>>(
        counts, N, W1, Wp1, W2, Wp2, W3, Wp3);

    // ---- CSR build ----
    hist_kernel<<<(E + 255) / 256, 256, 0, stream>>>(edst, counts, E);
    const int NB = (N + 2047) / 2048;  // 25
    scan1_kernel<<<NB, 256, 0, stream>>>(counts, off, bsum, N);
    scan2_kernel<<<1, 64, 0, stream>>>(bsum, boff, NB);
    scan3_kernel<<<(N + 255) / 256, 256, 0, stream>>>(off, cursor, boff, N, E);
    fill_kernel<<<(E + 255) / 256, 256, 0, stream>>>(esrc, edst, ew, cursor, csr, E);

    const int gemm_blocks = (N + 63) / 64;

    // ---- layer 1 (cast fused into GEMM) ----
    gemm_mfma<128, true><<<gemm_blocks, 256, 0, stream>>>(x, Wp1, Sb, N);
    spmm128_kernel<<<(N + 3) / 4, 256, 0, stream>>>((const uint*)Sb, off, csr, b1, (uint*)Hb, N);

    // ---- layer 2 ----
    gemm_mfma<128, false><<<gemm_blocks, 256, 0, stream>>>(Hb, Wp2, Sb, N);
    spmm128_kernel<<<(N + 3) / 4, 256, 0, stream>>>((const uint*)Sb, off, csr, b2, (uint*)Hb, N);

    // ---- layer 3 ----
    gemm_mfma<64, false><<<gemm_blocks, 256, 0, stream>>>(Hb, Wp3, Sb, N);
    spmm64_kernel<<<(N + 3) / 4, 256, 0, stream>>>(Sb, off, csr, b3, (float*)d_out, N);
}

// Round 5
// 215.898 us; speedup vs baseline: 2.4478x; 1.1277x over previous
//
#include <hip/hip_runtime.h>
#include <cstdint>
#include <cstddef>

typedef __attribute__((ext_vector_type(8))) short short8v;
typedef __attribute__((ext_vector_type(4))) float f32x4;

__device__ inline uint bf16_rne(float f) {
    uint u = __float_as_uint(f);
    return (u + 0x7fffu + ((u >> 16) & 1u)) >> 16;
}
__device__ inline float bf16lo_to_f(uint v) { return __uint_as_float(v << 16); }
__device__ inline float bf16hi_to_f(uint v) { return __uint_as_float(v & 0xffff0000u); }

// ---------------- init: zero counts + pack all three weight matrices ----------------
// pack W[128 x NC] f32 into MFMA B-fragment order (bf16):
// Wp[((c*4+kb)*64 + l)*8 + j] = W[(kb*32 + (l>>4)*8 + j)*NC + c*16 + (l&15)]
__device__ inline void pack_one(const float* __restrict__ W, ushort* __restrict__ Wp,
                                int NC, int i) {
    int j = i & 7, l = (i >> 3) & 63, kb = (i >> 9) & 3, c = i >> 11;
    int row = kb * 32 + ((l >> 4) & 3) * 8 + j;
    int col = c * 16 + (l & 15);
    Wp[i] = (ushort)bf16_rne(W[row * NC + col]);
}

__global__ void init_kernel(int* __restrict__ counts, int N,
                            const float* __restrict__ W1, ushort* __restrict__ Wp1,
                            const float* __restrict__ W2, ushort* __restrict__ Wp2,
                            const float* __restrict__ W3, ushort* __restrict__ Wp3) {
    int i = blockIdx.x * blockDim.x + threadIdx.x;
    if (i < N) counts[i] = 0;
    int zblocks = (N + 255) >> 8;
    int p = i - zblocks * 256;
    if (p >= 0) {
        if (p < 16384) pack_one(W1, Wp1, 128, p);
        else if (p < 32768) pack_one(W2, Wp2, 128, p - 16384);
        else if (p < 40960) pack_one(W3, Wp3, 64, p - 32768);
    }
}

// ---------------- CSR build ----------------

// histogram + per-edge rank (rank store is coalesced)
__global__ void hist_kernel(const int* __restrict__ dst, int* __restrict__ counts,
                            int* __restrict__ rank, int E) {
    int i = blockIdx.x * blockDim.x + threadIdx.x;
    if (i < E) rank[i] = atomicAdd(&counts[dst[i]], 1);
}

// 2048 elements per block (256 threads x 8), exclusive scan within block
__global__ void scan1_kernel(const int* __restrict__ counts, int* __restrict__ off,
                             int* __restrict__ bsum, int N) {
    __shared__ int sh[256];
    const int tid = threadIdx.x;
    const int base = blockIdx.x * 2048 + tid * 8;
    int v[8];
    int tsum = 0;
#pragma unroll
    for (int j = 0; j < 8; ++j) {
        int i = base + j;
        v[j] = (i < N) ? counts[i] : 0;
        tsum += v[j];
    }
    sh[tid] = tsum;
    __syncthreads();
    for (int d = 1; d < 256; d <<= 1) {
        int t = (tid >= d) ? sh[tid - d] : 0;
        __syncthreads();
        sh[tid] += t;
        __syncthreads();
    }
    int excl = sh[tid] - tsum;
    if (tid == 255) bsum[blockIdx.x] = sh[255];
    int run = excl;
#pragma unroll
    for (int j = 0; j < 8; ++j) {
        int i = base + j;
        if (i < N) off[i] = run;
        run += v[j];
    }
}

// single-wave scan of block sums (NB <= 64)
__global__ void scan2_kernel(const int* __restrict__ bsum, int* __restrict__ boff, int NB) {
    int lane = threadIdx.x;
    int orig = (lane < NB) ? bsum[lane] : 0;
    int v = orig;
#pragma unroll
    for (int d = 1; d < 64; d <<= 1) {
        int t = __shfl_up(v, d);
        if (lane >= d) v += t;
    }
    if (lane < NB) boff[lane] = v - orig;  // exclusive
}

__global__ void scan3_kernel(int* __restrict__ off, const int* __restrict__ boff,
                             int N, int E) {
    int i = blockIdx.x * blockDim.x + threadIdx.x;
    if (i < N) off[i] += boff[i >> 11];
    if (i == 0) off[N] = E;
}

// XCD-bucketed fill: bucket = blockIdx & 7 (round-robin XCD mapping).
// Each bucket owns a contiguous node range; its blocks scan the edge list and
// write only csr positions in their range -> csr lines are single-XCD-written
// (no cross-L2 write amplification). No atomics (rank precomputed in hist).
__global__ void fill_kernel(const int* __restrict__ src, const int* __restrict__ dst,
                            const float* __restrict__ w, const int* __restrict__ rank,
                            const int* __restrict__ off, uint* __restrict__ csr,
                            int E, int N) {
    const int bucket = blockIdx.x & 7;
    const int slice = blockIdx.x >> 3;
    const int nsl = gridDim.x >> 3;
    const int lo = (int)((long)bucket * N / 8);
    const int hi = (int)((long)(bucket + 1) * N / 8);
    const unsigned range = (unsigned)(hi - lo);

    const int E4 = E >> 2;
    const int chunk = (E4 + nsl - 1) / nsl;
    const int b4 = slice * chunk;
    const int e4 = min(E4, b4 + chunk);

    const int4* dst4 = (const int4*)dst;

#define FILL_ONE(idx, dv)                                                     \
    if ((unsigned)((dv) - lo) < range) {                                      \
        csr[off[dv] + rank[idx]] = (bf16_rne(w[idx]) << 16) | (uint)src[idx]; \
    }

    for (int q = b4 + threadIdx.x; q < e4; q += 256) {
        int4 d = dst4[q];
        int i = q * 4;
        FILL_ONE(i + 0, d.x);
        FILL_ONE(i + 1, d.y);
        FILL_ONE(i + 2, d.z);
        FILL_ONE(i + 3, d.w);
    }
    // tail (E not multiple of 4): slice 0 handles it
    if (slice == 0 && threadIdx.x < (E & 3)) {
        int i = (E & ~3) + threadIdx.x;
        int dv = dst[i];
        FILL_ONE(i, dv);
    }
#undef FILL_ONE
}

// ---------------- MFMA GEMM: S[M x NC] (bf16) = X[M x 128] @ Wp ----------------
// 256 threads = 4 waves; 64 rows per block (16 per wave); W staged in LDS.
// F32IN: input is f32 (layer 1, cast fused); else bf16.
template <int NC, bool F32IN>
__global__ __launch_bounds__(256) void gemm_mfma(const void* __restrict__ Xin,
                                                 const ushort* __restrict__ Wp,
                                                 ushort* __restrict__ Out, int M) {
    __shared__ ushort WL[128 * NC];
    const int t = threadIdx.x;
    {
        const uint4* srcp = (const uint4*)Wp;
        uint4* dstp = (uint4*)WL;
#pragma unroll
        for (int i = 0; i < NC / 16; ++i) dstp[t + i * 256] = srcp[t + i * 256];
    }
    __syncthreads();

    const int wave = t >> 6, l = t & 63;
    const int lr = l & 15, lh = l >> 4;
    const int rowbase = blockIdx.x * 64 + wave * 16;
    const int arow_idx = min(rowbase + lr, M - 1);  // clamp: avoid OOB read on tail block

    short8v a[4];
    if (F32IN) {
        const float* arow = (const float*)Xin + (size_t)arow_idx * 128 + lh * 8;
#pragma unroll
        for (int kb = 0; kb < 4; ++kb) {
            float4 u = *(const float4*)(arow + kb * 32);
            float4 v = *(const float4*)(arow + kb * 32 + 4);
            short8v av;
            av[0] = (short)bf16_rne(u.x); av[1] = (short)bf16_rne(u.y);
            av[2] = (short)bf16_rne(u.z); av[3] = (short)bf16_rne(u.w);
            av[4] = (short)bf16_rne(v.x); av[5] = (short)bf16_rne(v.y);
            av[6] = (short)bf16_rne(v.z); av[7] = (short)bf16_rne(v.w);
            a[kb] = av;
        }
    } else {
        const ushort* arow = (const ushort*)Xin + (size_t)arow_idx * 128 + lh * 8;
#pragma unroll
        for (int kb = 0; kb < 4; ++kb) a[kb] = *(const short8v*)(arow + kb * 32);
    }

    f32x4 acc[NC / 16];
#pragma unroll
    for (int c = 0; c < NC / 16; ++c) acc[c] = (f32x4){0.f, 0.f, 0.f, 0.f};

#pragma unroll
    for (int c = 0; c < NC / 16; ++c)
#pragma unroll
        for (int kb = 0; kb < 4; ++kb) {
            short8v b = *(const short8v*)(WL + ((c * 4 + kb) * 64 + l) * 8);
            acc[c] = __builtin_amdgcn_mfma_f32_16x16x32_bf16(a[kb], b, acc[c], 0, 0, 0);
        }

#pragma unroll
    for (int c = 0; c < NC / 16; ++c)
#pragma unroll
        for (int i = 0; i < 4; ++i) {
            int row = rowbase + lh * 4 + i;
            if (row < M) Out[(size_t)row * NC + c * 16 + lr] = (ushort)bf16_rne(acc[c][i]);
        }
}

// ---------------- SpMM (gather) D=128 bf16 + bias+relu -> bf16 ----------------
__global__ void spmm128_kernel(const uint* __restrict__ S, const int* __restrict__ off,
                               const uint* __restrict__ csr, const float* __restrict__ bias,
                               uint* __restrict__ Out, int N) {
    const int node = blockIdx.x * (blockDim.x >> 6) + (threadIdx.x >> 6);
    const int lane = threadIdx.x & 63;
    if (node >= N) return;
    const int e0 = off[node];
    const int e1 = off[node + 1];
    float ax = 0.f, ay = 0.f;
    int e = e0;

#define EDGE128(pk)                                                  \
    {                                                                \
        uint _p = (pk);                                              \
        float _w = __uint_as_float(_p & 0xffff0000u);                \
        uint _v = S[(size_t)(_p & 0xffffu) * 64 + lane];             \
        ax = fmaf(_w, bf16lo_to_f(_v), ax);                          \
        ay = fmaf(_w, bf16hi_to_f(_v), ay);                          \
    }

    while (e < e1 && (e & 3)) { EDGE128(csr[e]); ++e; }
    for (; e + 8 <= e1; e += 8) {
        uint4 c0 = *(const uint4*)(csr + e);
        uint4 c1 = *(const uint4*)(csr + e + 4);
        EDGE128(c0.x); EDGE128(c0.y); EDGE128(c0.z); EDGE128(c0.w);
        EDGE128(c1.x); EDGE128(c1.y); EDGE128(c1.z); EDGE128(c1.w);
    }
    for (; e + 4 <= e1; e += 4) {
        uint4 c0 = *(const uint4*)(csr + e);
        EDGE128(c0.x); EDGE128(c0.y); EDGE128(c0.z); EDGE128(c0.w);
    }
    for (; e < e1; ++e) EDGE128(csr[e]);
#undef EDGE128

    float2 bv = ((const float2*)bias)[lane];
    ax = fmaxf(ax + bv.x, 0.f);
    ay = fmaxf(ay + bv.y, 0.f);
    Out[(size_t)node * 64 + lane] = (bf16_rne(ay) << 16) | bf16_rne(ax);
}

// ---------------- SpMM D=64 bf16 + bias + log_softmax -> f32 ----------------
__global__ void spmm64_kernel(const ushort* __restrict__ S, const int* __restrict__ off,
                              const uint* __restrict__ csr, const float* __restrict__ bias,
                              float* __restrict__ Out, int N) {
    const int node = blockIdx.x * (blockDim.x >> 6) + (threadIdx.x >> 6);
    const int lane = threadIdx.x & 63;
    if (node >= N) return;
    const int e0 = off[node];
    const int e1 = off[node + 1];
    float acc = 0.f;
    int e = e0;

#define EDGE64(pk)                                                              \
    {                                                                           \
        uint _p = (pk);                                                         \
        float _w = __uint_as_float(_p & 0xffff0000u);                           \
        acc = fmaf(_w, bf16lo_to_f((uint)S[(size_t)(_p & 0xffffu) * 64 + lane]), acc); \
    }

    while (e < e1 && (e & 3)) { EDGE64(csr[e]); ++e; }
    for (; e + 8 <= e1; e += 8) {
        uint4 c0 = *(const uint4*)(csr + e);
        uint4 c1 = *(const uint4*)(csr + e + 4);
        EDGE64(c0.x); EDGE64(c0.y); EDGE64(c0.z); EDGE64(c0.w);
        EDGE64(c1.x); EDGE64(c1.y); EDGE64(c1.z); EDGE64(c1.w);
    }
    for (; e + 4 <= e1; e += 4) {
        uint4 c0 = *(const uint4*)(csr + e);
        EDGE64(c0.x); EDGE64(c0.y); EDGE64(c0.z); EDGE64(c0.w);
    }
    for (; e < e1; ++e) EDGE64(csr[e]);
#undef EDGE64

    float v = acc + bias[lane];
    float m = v;
#pragma unroll
    for (int d = 32; d >= 1; d >>= 1) m = fmaxf(m, __shfl_xor(m, d));
    float ex = __expf(v - m);
    float s = ex;
#pragma unroll
    for (int d = 32; d >= 1; d >>= 1) s += __shfl_xor(s, d);
    Out[(size_t)node * 64 + lane] = (v - m) - __logf(s);
}

// ---------------- launch ----------------

extern "C" void kernel_launch(void* const* d_in, const int* in_sizes, int n_in,
                              void* d_out, int out_size, void* d_ws, size_t ws_size,
                              hipStream_t stream) {
    const float* x  = (const float*)d_in[0];
    const int* esrc = (const int*)d_in[1];
    const int* edst = (const int*)d_in[2];
    const float* ew = (const float*)d_in[3];
    const float* W1 = (const float*)d_in[4];
    const float* b1 = (const float*)d_in[5];
    const float* W2 = (const float*)d_in[6];
    const float* b2 = (const float*)d_in[7];
    const float* W3 = (const float*)d_in[8];
    const float* b3 = (const float*)d_in[9];

    const int N = in_sizes[0] / 128;  // 50000
    const int E = in_sizes[1];        // 800000

    // workspace carve (256B aligned)
    char* ws = (char*)d_ws;
    auto alloc = [&](size_t bytes) {
        char* p = ws;
        ws += (bytes + 255) & ~(size_t)255;
        return p;
    };
    int* counts  = (int*)alloc((size_t)N * 4);
    int* off     = (int*)alloc((size_t)(N + 1) * 4);
    int* rank    = (int*)alloc((size_t)E * 4);
    int* bsum    = (int*)alloc(64 * 4);
    int* boff    = (int*)alloc(64 * 4);
    uint* csr    = (uint*)alloc((size_t)E * 4);
    ushort* Sb   = (ushort*)alloc((size_t)N * 128 * 2);
    ushort* Hb   = (ushort*)alloc((size_t)N * 128 * 2);
    ushort* Wp1  = (ushort*)alloc(128 * 128 * 2);
    ushort* Wp2  = (ushort*)alloc(128 * 128 * 2);
    ushort* Wp3  = (ushort*)alloc(128 * 64 * 2);
    (void)ws_size;

    // ---- init (zero counts + pack weights) ----
    const int zblocks = (N + 255) / 256;
    init_kernel<<<zblocks + (40960 + 255) / 256, 256, 0, stream>>>(
        counts, N, W1, Wp1, W2, Wp2, W3, Wp3);

    // ---- CSR build ----
    hist_kernel<<<(E + 255) / 256, 256, 0, stream>>>(edst, counts, rank, E);
    const int NB = (N + 2047) / 2048;  // 25
    scan1_kernel<<<NB, 256, 0, stream>>>(counts, off, bsum, N);
    scan2_kernel<<<1, 64, 0, stream>>>(bsum, boff, NB);
    scan3_kernel<<<(N + 255) / 256, 256, 0, stream>>>(off, boff, N, E);
    fill_kernel<<<128 * 8, 256, 0, stream>>>(esrc, edst, ew, rank, off, csr, E, N);

    const int gemm_blocks = (N + 63) / 64;

    // ---- layer 1 (cast fused into GEMM) ----
    gemm_mfma<128, true><<<gemm_blocks, 256, 0, stream>>>(x, Wp1, Sb, N);
    spmm128_kernel<<<(N + 3) / 4, 256, 0, stream>>>((const uint*)Sb, off, csr, b1, (uint*)Hb, N);

    // ---- layer 2 ----
    gemm_mfma<128, false><<<gemm_blocks, 256, 0, stream>>>(Hb, Wp2, Sb, N);
    spmm128_kernel<<<(N + 3) / 4, 256, 0, stream>>>((const uint*)Sb, off, csr, b2, (uint*)Hb, N);

    // ---- layer 3 ----
    gemm_mfma<64, false><<<gemm_blocks, 256, 0, stream>>>(Hb, Wp3, Sb, N);
    spmm64_kernel<<<(N + 3) / 4, 256, 0, stream>>>(Sb, off, csr, b3, (float*)d_out, N);
}